// Round 7
// baseline (630.936 us; speedup 1.0000x reference)
//
#include <hip/hip_runtime.h>
#include <cstdint>
#include <cstddef>

// Problem constants (B=2, S=4096 -> T=8192 tokens)
#define T_TOK 8192
#define DIM   1024   // D
#define NE    8      // experts
#define FF    2048   // F
#define TOPK  2

typedef __bf16 bf16x8 __attribute__((ext_vector_type(8)));
typedef float  floatx4 __attribute__((ext_vector_type(4)));

__device__ __forceinline__ unsigned short f2bf(float f) {
  unsigned int u = __float_as_uint(f);
  unsigned int r = 0x7FFFu + ((u >> 16) & 1u);   // round-to-nearest-even
  return (unsigned short)((u + r) >> 16);
}

__device__ __forceinline__ void gl_lds16(const void* g, void* l) {
  __builtin_amdgcn_global_load_lds(
      (__attribute__((address_space(1))) void*)g,
      (__attribute__((address_space(3))) void*)l,
      16, 0, 0);
}

// ---------------------------------------------------------------------------
// Fused transpose + f32->bf16 for BOTH weights, 64x64 tiles, vectorized:
// float4 global loads (16B/lane), ushort4 global stores (8B/lane).
// z<8 : w1 [e][D][F] -> w1t [e][F][D]   (R=DIM, C=FF)
// z>=8: w2 [e][F][D] -> w2t [e][D][F]   (R=FF, C=DIM)
// ---------------------------------------------------------------------------
__global__ __launch_bounds__(256) void transpose2_bf16_kernel(
    const float* __restrict__ w1, unsigned short* __restrict__ w1t,
    const float* __restrict__ w2, unsigned short* __restrict__ w2t)
{
  __shared__ unsigned short tile[64][68];   // 8.5 KB
  int z = blockIdx.z;
  int e = z & 7, sel = z >> 3;
  int R = sel ? FF : DIM;
  int C = sel ? DIM : FF;
  const float* inp = (sel ? w2 : w1) + (size_t)e * R * C;
  unsigned short* op = (sel ? w2t : w1t) + (size_t)e * R * C;
  int nc = C >> 6;                       // 64-col tiles along C
  int bx = blockIdx.x;
  int c0 = (bx % nc) * 64, r0 = (bx / nc) * 64;
  int t4 = threadIdx.x & 15, ry = threadIdx.x >> 4;   // 16 x 16
  #pragma unroll
  for (int p = 0; p < 4; ++p) {
    int r = ry + p * 16;
    float4 v = *(const float4*)&inp[(size_t)(r0 + r) * C + c0 + t4 * 4];
    ushort4 sv;
    sv.x = f2bf(v.x); sv.y = f2bf(v.y); sv.z = f2bf(v.z); sv.w = f2bf(v.w);
    *(ushort4*)&tile[r][t4 * 4] = sv;
  }
  __syncthreads();
  #pragma unroll
  for (int p = 0; p < 4; ++p) {
    int cy = ry + p * 16;
    ushort4 s;
    s.x = tile[t4 * 4 + 0][cy];
    s.y = tile[t4 * 4 + 1][cy];
    s.z = tile[t4 * 4 + 2][cy];
    s.w = tile[t4 * 4 + 3][cy];
    *(ushort4*)&op[(size_t)(c0 + cy) * R + r0 + t4 * 4] = s;
  }
}

// ---------------------------------------------------------------------------
// Gating pass 1: one wave per token (4 waves/block). gw staged TRANSPOSED in
// LDS. f64 logit accumulation (top-2 robust vs np ref). Fused x->bf16.
// Block 0 zeroes cnt[] for the parallel assign pass.
// ---------------------------------------------------------------------------
__global__ __launch_bounds__(256) void gate_kernel(
    const float* __restrict__ x, const float* __restrict__ gw,
    unsigned short* __restrict__ xb, int* __restrict__ tokExp,
    float* __restrict__ tokW, int* __restrict__ cnt)
{
  __shared__ float gwT[NE][DIM];   // 32 KB
  int tid = threadIdx.x;
  if (blockIdx.x == 0 && tid < NE) cnt[tid] = 0;
  for (int i = tid; i < DIM * NE; i += 256) {
    int d = i >> 3, e = i & 7;
    gwT[e][d] = gw[i];
  }
  __syncthreads();

  int wv = tid >> 6, lane = tid & 63;
  int t = blockIdx.x * 4 + wv;
  const float* xrow = x + (size_t)t * DIM;
  unsigned short* xbrow = xb + (size_t)t * DIM;

  double acc[NE];
  for (int e = 0; e < NE; ++e) acc[e] = 0.0;

  for (int j = 0; j < 4; ++j) {
    float4 xv = ((const float4*)xrow)[j * 64 + lane];
    ushort4 s;
    s.x = f2bf(xv.x); s.y = f2bf(xv.y); s.z = f2bf(xv.z); s.w = f2bf(xv.w);
    ((ushort4*)xbrow)[j * 64 + lane] = s;
    double xd0 = (double)xv.x, xd1 = (double)xv.y;
    double xd2 = (double)xv.z, xd3 = (double)xv.w;
    for (int e = 0; e < NE; ++e) {
      float4 g = ((const float4*)&gwT[e][0])[j * 64 + lane];
      acc[e] += xd0 * (double)g.x + xd1 * (double)g.y +
                xd2 * (double)g.z + xd3 * (double)g.w;
    }
  }

  for (int s = 32; s > 0; s >>= 1)
    for (int e = 0; e < NE; ++e)
      acc[e] += __shfl_down(acc[e], s, 64);

  if (lane == 0) {
    int e0 = 0; double v0 = acc[0];
    for (int e = 1; e < NE; ++e) if (acc[e] > v0) { v0 = acc[e]; e0 = e; }
    int e1 = -1; double v1 = -1.0e300;
    for (int e = 0; e < NE; ++e) {
      if (e == e0) continue;
      if (acc[e] > v1) { v1 = acc[e]; e1 = e; }
    }
    float a = (float)v0, b = (float)v1;
    float eb = __expf(b - a);
    float den = 1.0f + eb;
    tokExp[t] = e0 | (e1 << 8);
    tokW[2 * t + 0] = 1.0f / den;
    tokW[2 * t + 1] = eb / den;
  }
}

// ---------------------------------------------------------------------------
// Gating pass 2 (PARALLEL): ballot ranks + ONE atomicAdd per expert per wave.
// Slot order nondeterministic but output bitwise invariant.
// ---------------------------------------------------------------------------
__global__ __launch_bounds__(256) void assign_kernel(
    const int* __restrict__ tokExp, int* __restrict__ tokEnc,
    int* __restrict__ tIdx, int* __restrict__ cnt)
{
  int t = blockIdx.x * 256 + threadIdx.x;
  int lane = threadIdx.x & 63;
  unsigned long long below = (1ull << lane) - 1ull;
  int enc = tokExp[t];
  int e0 = enc & 0xFF, e1 = (enc >> 8) & 0xFF;
  int s0 = 0, s1 = 0;
  for (int e = 0; e < NE; ++e) {
    unsigned long long m0 = __ballot(e0 == e);
    unsigned long long m1 = __ballot(e1 == e);
    int c0 = __popcll(m0), c1 = __popcll(m1);
    int base = 0;
    if (lane == 0 && (c0 + c1) > 0)
      base = atomicAdd(&cnt[e], c0 + c1);
    base = __shfl(base, 0, 64);
    if (e0 == e) s0 = base + __popcll(m0 & below);
    if (e1 == e) s1 = base + c0 + __popcll(m1 & below);
  }
  tokEnc[2 * t + 0] = (e0 << 16) | s0;
  tokEnc[2 * t + 1] = (e1 << 16) | s1;
  tIdx[e0 * T_TOK + s0] = t;
  tIdx[e1 * T_TOK + s1] = t;
}

// ---------------------------------------------------------------------------
// 256x256x(K) MFMA core, 8-phase schedule (T3+T4+T5), 512 threads / 8 waves.
// VERIFIED-CORRECT ON HW (round 2, passed). Counted vmcnt(6): 3 half-tiles
// stay in flight across every K-tile boundary; raw s_barrier, no drain.
// Stage schedule per frame computing (t,t+1):
//   ph0: A(t+1)h0            ph4: A(t+2)h0
//   ph1: A(t+1)h1 B(t+2)h0   ph5: A(t+2)h1
//   ph2: B(t+2)h1            ph6: B(t+3)h0
//   ph3: -                   ph7: B(t+3)h1
// ---------------------------------------------------------------------------
template<int KDIM>
__device__ __forceinline__ void mfma_core(
    const unsigned short* (&agp)[4], const unsigned short* (&bgp)[4],
    unsigned short* smem, floatx4 (&acc)[8][4])
{
  constexpr int NKT = KDIM / 64;    // K-tiles (always even here)
  const int tid = threadIdx.x, lane = tid & 63, w = tid >> 6;
  const int wm = w >> 2, wn = w & 3;
  const int quad = lane >> 4, li = lane & 15;

  unsigned short (*As)[8][256][8] = (unsigned short (*)[8][256][8])smem;
  unsigned short (*Bs)[8][256][8] = (unsigned short (*)[8][256][8])(smem + 32768);

  #define STAGE_A(BUF, KT, HALF) do { \
    gl_lds16(agp[(HALF)*2+0] + (KT)*64 + w*8, &As[BUF][w][(HALF)*128 +  0][0]); \
    gl_lds16(agp[(HALF)*2+1] + (KT)*64 + w*8, &As[BUF][w][(HALF)*128 + 64][0]); } while(0)
  #define STAGE_B(BUF, KT, HALF) do { \
    gl_lds16(bgp[(HALF)*2+0] + (KT)*64 + w*8, &Bs[BUF][w][(HALF)*128 +  0][0]); \
    gl_lds16(bgp[(HALF)*2+1] + (KT)*64 + w*8, &Bs[BUF][w][(HALF)*128 + 64][0]); } while(0)

  // Prologue order matters for the vmcnt(6) invariant: B(0),A(0),B(1).
  STAGE_B(0, 0, 0); STAGE_B(0, 0, 1);
  STAGE_A(0, 0, 0); STAGE_A(0, 0, 1);
  STAGE_B(1, 1, 0); STAGE_B(1, 1, 1);

  for (int t0 = 0; t0 < NKT; t0 += 2) {
    // ---------- phases 0-3 : K-tile t0 (buf 0) ----------
    bf16x8 bf[4][2];
    #pragma unroll
    for (int q = 0; q < 4; ++q) {
      if (q == 0) STAGE_A(1, t0 + 1, 0);
      if (q == 1) { STAGE_A(1, t0 + 1, 1); if (t0 + 2 < NKT) STAGE_B(0, t0 + 2, 0); }
      if (q == 2) { if (t0 + 2 < NKT) STAGE_B(0, t0 + 2, 1); }
      if (q == 0) asm volatile("s_waitcnt vmcnt(6)" ::: "memory");
      asm volatile("s_barrier" ::: "memory");
      if (q == 0) {
        #pragma unroll
        for (int ni = 0; ni < 4; ++ni)
          #pragma unroll
          for (int kk = 0; kk < 2; ++kk)
            bf[ni][kk] = *(const bf16x8*)&Bs[0][kk * 4 + quad][wn * 64 + ni * 16 + li][0];
      }
      bf16x8 af[2][2];
      #pragma unroll
      for (int j = 0; j < 2; ++j)
        #pragma unroll
        for (int kk = 0; kk < 2; ++kk)
          af[j][kk] = *(const bf16x8*)&As[0][kk * 4 + quad][wm * 128 + (2 * q + j) * 16 + li][0];
      __builtin_amdgcn_s_setprio(1);
      #pragma unroll
      for (int j = 0; j < 2; ++j)
        #pragma unroll
        for (int ni = 0; ni < 4; ++ni)
          #pragma unroll
          for (int kk = 0; kk < 2; ++kk)
            acc[2 * q + j][ni] = __builtin_amdgcn_mfma_f32_16x16x32_bf16(
                af[j][kk], bf[ni][kk], acc[2 * q + j][ni], 0, 0, 0);
      __builtin_amdgcn_s_setprio(0);
      asm volatile("s_barrier" ::: "memory");
    }
    // ---------- phases 4-7 : K-tile t0+1 (buf 1) ----------
    #pragma unroll
    for (int q = 0; q < 4; ++q) {
      if (q == 0) { if (t0 + 2 < NKT) STAGE_A(0, t0 + 2, 0); }
      if (q == 1) { if (t0 + 2 < NKT) STAGE_A(0, t0 + 2, 1); }
      if (q == 2) { if (t0 + 3 < NKT) STAGE_B(1, t0 + 3, 0); }
      if (q == 3) { if (t0 + 3 < NKT) STAGE_B(1, t0 + 3, 1); }
      if (q == 0) {
        if (t0 + 2 < NKT) asm volatile("s_waitcnt vmcnt(6)" ::: "memory");
        else              asm volatile("s_waitcnt vmcnt(0)" ::: "memory");
      }
      asm volatile("s_barrier" ::: "memory");
      if (q == 0) {
        #pragma unroll
        for (int ni = 0; ni < 4; ++ni)
          #pragma unroll
          for (int kk = 0; kk < 2; ++kk)
            bf[ni][kk] = *(const bf16x8*)&Bs[1][kk * 4 + quad][wn * 64 + ni * 16 + li][0];
      }
      bf16x8 af[2][2];
      #pragma unroll
      for (int j = 0; j < 2; ++j)
        #pragma unroll
        for (int kk = 0; kk < 2; ++kk)
          af[j][kk] = *(const bf16x8*)&As[1][kk * 4 + quad][wm * 128 + (2 * q + j) * 16 + li][0];
      __builtin_amdgcn_s_setprio(1);
      #pragma unroll
      for (int j = 0; j < 2; ++j)
        #pragma unroll
        for (int ni = 0; ni < 4; ++ni)
          #pragma unroll
          for (int kk = 0; kk < 2; ++kk)
            acc[2 * q + j][ni] = __builtin_amdgcn_mfma_f32_16x16x32_bf16(
                af[j][kk], bf[ni][kk], acc[2 * q + j][ni], 0, 0, 0);
      __builtin_amdgcn_s_setprio(0);
      asm volatile("s_barrier" ::: "memory");
    }
  }
  #undef STAGE_A
  #undef STAGE_B
}

// ---------------------------------------------------------------------------
// GEMM1: h[row][f] = silu( sum_d xb[tok(row)][d] * w1t[e][f][d] )   (bf16 out)
// 256x256 8-phase core (verified r2) + FIXED L2-aware decode (the r2 failure
// was ordering: m-fastest gave FETCH 142MB / WRITE 344MB). Now, per expert:
// phase = n-half (2MB B L2-resident) outer, m middle, nl inner (A-tile
// shared by 4 consecutive blocks). 1 blk/CU x 32 CU/XCD = whole phase
// co-resident -> h-row writes merge.
// ---------------------------------------------------------------------------
__global__ __launch_bounds__(512, 2) void gemm1_kernel(
    const unsigned short* __restrict__ xb,   // [T][D] bf16
    const unsigned short* __restrict__ w1t,  // [E][F][D] bf16
    unsigned short* __restrict__ h,          // [2T][F] bf16 (compacted)
    const int* __restrict__ tIdx, const int* __restrict__ cnt)
{
  // g = (((phase*32 + m)*4 + nl) << 3) | e
  int g = blockIdx.x;
  int e = g & 7;
  int b = g >> 3;              // 0..255
  int nl = b & 3;              // n within half (innermost)
  int m = (b >> 2) & 31;       // M-tile (middle)
  int phase = b >> 7;          // n-half (outermost)
  int count = cnt[e];
  int r0 = m * 256;
  if (r0 >= count) return;
  int n0 = (phase * 4 + nl) * 256;

  __shared__ __align__(16) unsigned short smem[2 * 8 * 256 * 8 * 2];  // 128 KB

  int tid = threadIdx.x, lane = tid & 63;
  const unsigned short* agp[4];
  const unsigned short* bgp[4];
  #pragma unroll
  for (int gq = 0; gq < 4; ++gq) {
    int r = r0 + gq * 64 + lane; if (r > count - 1) r = count - 1;
    agp[gq] = xb + (size_t)tIdx[e * T_TOK + r] * DIM;
    bgp[gq] = w1t + ((size_t)e * FF + (n0 + gq * 64 + lane)) * DIM;
  }

  floatx4 acc[8][4];
  #pragma unroll
  for (int mi = 0; mi < 8; ++mi)
    #pragma unroll
    for (int ni = 0; ni < 4; ++ni)
      #pragma unroll
      for (int qq = 0; qq < 4; ++qq) acc[mi][ni][qq] = 0.0f;

  mfma_core<DIM>(agp, bgp, smem, acc);

  size_t hb = 0;
  for (int i = 0; i < e; ++i) hb += cnt[i];
  int w = tid >> 6, wm = w >> 2, wn = w & 3, quad = lane >> 4, li = lane & 15;
  for (int mi = 0; mi < 8; ++mi) {
    int rowb = wm * 128 + mi * 16 + quad * 4;
    for (int rr = 0; rr < 4; ++rr) {
      int r = r0 + rowb + rr;
      if (r >= count) continue;
      unsigned short* hrow = h + (hb + r) * FF + n0 + wn * 64 + li;
      for (int ni = 0; ni < 4; ++ni) {
        float v = acc[mi][ni][rr];
        float s = v / (1.0f + __expf(-v));   // silu
        hrow[ni * 16] = f2bf(s);
      }
    }
  }
}

// ---------------------------------------------------------------------------
// GEMM2: yv[row][d] = sum_f h[row][f] * w2t[e][d][f]    (f32 out)
// ROUND-4 MEASURED-BEST structure (128x128, single-buffer, 4 blk/CU).
// ---------------------------------------------------------------------------
__global__ __launch_bounds__(256, 4) void gemm2_kernel(
    const unsigned short* __restrict__ h,    // [2T][F] bf16
    const unsigned short* __restrict__ w2t,  // [E][D][F] bf16
    float* __restrict__ yv,                  // [2T][D] f32
    const int* __restrict__ cnt)
{
  // decode swizzled 1-D id: g = (phase*256 + m*4 + nl)*8 + e
  int g = blockIdx.x;
  int e = g & 7;
  int b = g >> 3;              // 0..511
  int phase = b >> 8;          // 0..1
  int m = (b >> 2) & 63;       // 0..63
  int nl = b & 3;              // 0..3
  int count = cnt[e];
  int r0 = m * 128;
  if (r0 >= count) return;
  int n0 = (phase * 4 + nl) * 128;

  __shared__ __align__(16) unsigned short As[8][128][8];   // 16 KB
  __shared__ __align__(16) unsigned short Bs[8][128][8];   // 16 KB

  int tid = threadIdx.x, lane = tid & 63, w = tid >> 6;
  int wr = w >> 1, wc = w & 1;
  int quad = lane >> 4, li = lane & 15;
  size_t yb = 0;
  for (int i = 0; i < e; ++i) yb += cnt[i];

  const unsigned short* ag[2];
  const unsigned short* bg[2];
  for (int c = 0; c < 2; ++c) {
    int mm = c * 64 + lane;
    int r = r0 + mm; if (r > count - 1) r = count - 1;
    ag[c] = h + (yb + r) * FF;
    bg[c] = w2t + ((size_t)e * DIM + (n0 + mm)) * FF;
  }

  floatx4 acc[4][4];
  for (int mi = 0; mi < 4; ++mi)
    for (int ni = 0; ni < 4; ++ni)
      for (int q = 0; q < 4; ++q) acc[mi][ni][q] = 0.0f;

  for (int k0 = 0; k0 < FF; k0 += 64) {
    __syncthreads();
    for (int kk = 0; kk < 2; ++kk) {
      int kq = w + kk * 4;
      gl_lds16(ag[0] + k0 + kq * 8, &As[kq][0][0]);
      gl_lds16(ag[1] + k0 + kq * 8, &As[kq][64][0]);
      gl_lds16(bg[0] + k0 + kq * 8, &Bs[kq][0][0]);
      gl_lds16(bg[1] + k0 + kq * 8, &Bs[kq][64][0]);
    }
    __syncthreads();
    for (int ks = 0; ks < 2; ++ks) {
      bf16x8 af[4], bf[4];
      for (int mi = 0; mi < 4; ++mi)
        af[mi] = *(const bf16x8*)&As[ks * 4 + quad][wr * 64 + mi * 16 + li][0];
      for (int ni = 0; ni < 4; ++ni)
        bf[ni] = *(const bf16x8*)&Bs[ks * 4 + quad][wc * 64 + ni * 16 + li][0];
      for (int mi = 0; mi < 4; ++mi)
        for (int ni = 0; ni < 4; ++ni)
          acc[mi][ni] = __builtin_amdgcn_mfma_f32_16x16x32_bf16(
              af[mi], bf[ni], acc[mi][ni], 0, 0, 0);
    }
  }

  for (int mi = 0; mi < 4; ++mi) {
    int rowb = wr * 64 + mi * 16 + quad * 4;
    for (int rr = 0; rr < 4; ++rr) {
      int r = r0 + rowb + rr;
      if (r >= count) continue;
      float* yrow = yv + (yb + r) * DIM + n0 + wc * 64 + li;
      for (int ni = 0; ni < 4; ++ni)
        yrow[ni * 16] = acc[mi][ni][rr];
    }
  }
}

// ---------------------------------------------------------------------------
// Combine: out[t] = w0 * yv[row0] + w1 * yv[row1]
// ---------------------------------------------------------------------------
__global__ __launch_bounds__(256) void combine_kernel(
    const float* __restrict__ yv, const int* __restrict__ tokEnc,
    const float* __restrict__ tokW, const int* __restrict__ cnt,
    float* __restrict__ out)
{
  int t = blockIdx.x;
  int i = threadIdx.x;   // 256 threads x float4 = 1024 = D
  int enc0 = tokEnc[2 * t + 0], enc1 = tokEnc[2 * t + 1];
  float w0 = tokW[2 * t + 0], w1 = tokW[2 * t + 1];
  int x0 = enc0 >> 16, x1 = enc1 >> 16;
  int off0 = 0, off1 = 0, a = 0;
  for (int e = 0; e < NE; ++e) {
    if (e == x0) off0 = a;
    if (e == x1) off1 = a;
    a += cnt[e];
  }
  size_t row0 = (size_t)off0 + (enc0 & 0xFFFF);
  size_t row1 = (size_t)off1 + (enc1 & 0xFFFF);
  float4 va = ((const float4*)(yv + row0 * DIM))[i];
  float4 vb = ((const float4*)(yv + row1 * DIM))[i];
  float4 o;
  o.x = w0 * va.x + w1 * vb.x;
  o.y = w0 * va.y + w1 * vb.y;
  o.z = w0 * va.z + w1 * vb.z;
  o.w = w0 * va.w + w1 * vb.w;
  ((float4*)(out + (size_t)t * DIM))[i] = o;
}

// ---------------------------------------------------------------------------
extern "C" void kernel_launch(void* const* d_in, const int* in_sizes, int n_in,
                              void* d_out, int out_size, void* d_ws, size_t ws_size,
                              hipStream_t stream)
{
  const float* x  = (const float*)d_in[0];   // [T][D]
  const float* gw = (const float*)d_in[1];   // [D][E]
  const float* w1 = (const float*)d_in[2];   // [E][D][F]
  const float* w2 = (const float*)d_in[3];   // [E][F][D]
  float* out = (float*)d_out;                // [T][D]

  // workspace carve-up (256B aligned)
  size_t o = 0;
  auto alloc = [&](size_t bytes) {
    void* p = (char*)d_ws + o;
    o += (bytes + 255) & ~(size_t)255;
    return p;
  };
  unsigned short* xb   = (unsigned short*)alloc((size_t)T_TOK * DIM * 2);      // 16.8 MB
  unsigned short* w1t  = (unsigned short*)alloc((size_t)NE * DIM * FF * 2);    // 33.6 MB
  unsigned short* w2t  = (unsigned short*)alloc((size_t)NE * DIM * FF * 2);    // 33.6 MB
  unsigned short* hbuf = (unsigned short*)alloc((size_t)T_TOK * TOPK * FF * 2);// 67.1 MB
  float*          yv   = (float*)alloc((size_t)T_TOK * TOPK * DIM * 4);        // 67.1 MB
  int*   tIdx   = (int*)alloc((size_t)NE * T_TOK * 4);
  int*   tokEnc = (int*)alloc((size_t)2 * T_TOK * 4);
  float* tokW   = (float*)alloc((size_t)2 * T_TOK * 4);
  int*   tokExp = (int*)alloc((size_t)T_TOK * 4);
  int*   cnt    = (int*)alloc((size_t)NE * 4);

  // both weight transposes in ONE launch (z = expert | sel<<3), 64x64 tiles
  transpose2_bf16_kernel<<<dim3(512, 1, 2 * NE), 256, 0, stream>>>(w1, w1t, w2, w2t);

  gate_kernel<<<T_TOK / 4, 256, 0, stream>>>(x, gw, xb, tokExp, tokW, cnt);
  assign_kernel<<<T_TOK / 256, 256, 0, stream>>>(tokExp, tokEnc, tIdx, cnt);

  // gemm1: 256^2 8-phase, L2-aware order; grid covers worst-case count
  gemm1_kernel<<<NE * 2 * 32 * 4, 512, 0, stream>>>(xb, w1t, hbuf, tIdx, cnt);
  // gemm2: round-4 measured-best 128^2 structure
  gemm2_kernel<<<4096, 256, 0, stream>>>(hbuf, w2t, yv, cnt);
  combine_kernel<<<T_TOK, 256, 0, stream>>>(yv, tokEnc, tokW, cnt, out);
}

// Round 8
// 570.112 us; speedup vs baseline: 1.1067x; 1.1067x over previous
//
#include <hip/hip_runtime.h>
#include <cstdint>
#include <cstddef>

// Problem constants (B=2, S=4096 -> T=8192 tokens)
#define T_TOK 8192
#define DIM   1024   // D
#define NE    8      // experts
#define FF    2048   // F
#define TOPK  2

typedef __bf16 bf16x8 __attribute__((ext_vector_type(8)));
typedef float  floatx4 __attribute__((ext_vector_type(4)));

__device__ __forceinline__ unsigned short f2bf(float f) {
  unsigned int u = __float_as_uint(f);
  unsigned int r = 0x7FFFu + ((u >> 16) & 1u);   // round-to-nearest-even
  return (unsigned short)((u + r) >> 16);
}

__device__ __forceinline__ void gl_lds16(const void* g, void* l) {
  __builtin_amdgcn_global_load_lds(
      (__attribute__((address_space(1))) void*)g,
      (__attribute__((address_space(3))) void*)l,
      16, 0, 0);
}

// ---------------------------------------------------------------------------
// Fused transpose + f32->bf16 for BOTH weights, 64x64 tiles, vectorized:
// float4 global loads (16B/lane), ushort4 global stores (8B/lane).
// z<8 : w1 [e][D][F] -> w1t [e][F][D]   (R=DIM, C=FF)
// z>=8: w2 [e][F][D] -> w2t [e][D][F]   (R=FF, C=DIM)
// ---------------------------------------------------------------------------
__global__ __launch_bounds__(256) void transpose2_bf16_kernel(
    const float* __restrict__ w1, unsigned short* __restrict__ w1t,
    const float* __restrict__ w2, unsigned short* __restrict__ w2t)
{
  __shared__ unsigned short tile[64][68];   // 8.5 KB
  int z = blockIdx.z;
  int e = z & 7, sel = z >> 3;
  int R = sel ? FF : DIM;
  int C = sel ? DIM : FF;
  const float* inp = (sel ? w2 : w1) + (size_t)e * R * C;
  unsigned short* op = (sel ? w2t : w1t) + (size_t)e * R * C;
  int nc = C >> 6;                       // 64-col tiles along C
  int bx = blockIdx.x;
  int c0 = (bx % nc) * 64, r0 = (bx / nc) * 64;
  int t4 = threadIdx.x & 15, ry = threadIdx.x >> 4;   // 16 x 16
  #pragma unroll
  for (int p = 0; p < 4; ++p) {
    int r = ry + p * 16;
    float4 v = *(const float4*)&inp[(size_t)(r0 + r) * C + c0 + t4 * 4];
    ushort4 sv;
    sv.x = f2bf(v.x); sv.y = f2bf(v.y); sv.z = f2bf(v.z); sv.w = f2bf(v.w);
    *(ushort4*)&tile[r][t4 * 4] = sv;
  }
  __syncthreads();
  #pragma unroll
  for (int p = 0; p < 4; ++p) {
    int cy = ry + p * 16;
    ushort4 s;
    s.x = tile[t4 * 4 + 0][cy];
    s.y = tile[t4 * 4 + 1][cy];
    s.z = tile[t4 * 4 + 2][cy];
    s.w = tile[t4 * 4 + 3][cy];
    *(ushort4*)&op[(size_t)(c0 + cy) * R + r0 + t4 * 4] = s;
  }
}

// ---------------------------------------------------------------------------
// Gating pass 1: one wave per token (4 waves/block). gw staged TRANSPOSED in
// LDS. f64 logit accumulation (top-2 robust vs np ref). Fused x->bf16.
// Block 0 zeroes cnt[] for the parallel assign pass.
// ---------------------------------------------------------------------------
__global__ __launch_bounds__(256) void gate_kernel(
    const float* __restrict__ x, const float* __restrict__ gw,
    unsigned short* __restrict__ xb, int* __restrict__ tokExp,
    float* __restrict__ tokW, int* __restrict__ cnt)
{
  __shared__ float gwT[NE][DIM];   // 32 KB
  int tid = threadIdx.x;
  if (blockIdx.x == 0 && tid < NE) cnt[tid] = 0;
  for (int i = tid; i < DIM * NE; i += 256) {
    int d = i >> 3, e = i & 7;
    gwT[e][d] = gw[i];
  }
  __syncthreads();

  int wv = tid >> 6, lane = tid & 63;
  int t = blockIdx.x * 4 + wv;
  const float* xrow = x + (size_t)t * DIM;
  unsigned short* xbrow = xb + (size_t)t * DIM;

  double acc[NE];
  for (int e = 0; e < NE; ++e) acc[e] = 0.0;

  for (int j = 0; j < 4; ++j) {
    float4 xv = ((const float4*)xrow)[j * 64 + lane];
    ushort4 s;
    s.x = f2bf(xv.x); s.y = f2bf(xv.y); s.z = f2bf(xv.z); s.w = f2bf(xv.w);
    ((ushort4*)xbrow)[j * 64 + lane] = s;
    double xd0 = (double)xv.x, xd1 = (double)xv.y;
    double xd2 = (double)xv.z, xd3 = (double)xv.w;
    for (int e = 0; e < NE; ++e) {
      float4 g = ((const float4*)&gwT[e][0])[j * 64 + lane];
      acc[e] += xd0 * (double)g.x + xd1 * (double)g.y +
                xd2 * (double)g.z + xd3 * (double)g.w;
    }
  }

  for (int s = 32; s > 0; s >>= 1)
    for (int e = 0; e < NE; ++e)
      acc[e] += __shfl_down(acc[e], s, 64);

  if (lane == 0) {
    int e0 = 0; double v0 = acc[0];
    for (int e = 1; e < NE; ++e) if (acc[e] > v0) { v0 = acc[e]; e0 = e; }
    int e1 = -1; double v1 = -1.0e300;
    for (int e = 0; e < NE; ++e) {
      if (e == e0) continue;
      if (acc[e] > v1) { v1 = acc[e]; e1 = e; }
    }
    float a = (float)v0, b = (float)v1;
    float eb = __expf(b - a);
    float den = 1.0f + eb;
    tokExp[t] = e0 | (e1 << 8);
    tokW[2 * t + 0] = 1.0f / den;
    tokW[2 * t + 1] = eb / den;
  }
}

// ---------------------------------------------------------------------------
// Gating pass 2 (PARALLEL): ballot ranks + ONE atomicAdd per expert per wave.
// Slot order nondeterministic but output bitwise invariant.
// ---------------------------------------------------------------------------
__global__ __launch_bounds__(256) void assign_kernel(
    const int* __restrict__ tokExp, int* __restrict__ tokEnc,
    int* __restrict__ tIdx, int* __restrict__ cnt)
{
  int t = blockIdx.x * 256 + threadIdx.x;
  int lane = threadIdx.x & 63;
  unsigned long long below = (1ull << lane) - 1ull;
  int enc = tokExp[t];
  int e0 = enc & 0xFF, e1 = (enc >> 8) & 0xFF;
  int s0 = 0, s1 = 0;
  for (int e = 0; e < NE; ++e) {
    unsigned long long m0 = __ballot(e0 == e);
    unsigned long long m1 = __ballot(e1 == e);
    int c0 = __popcll(m0), c1 = __popcll(m1);
    int base = 0;
    if (lane == 0 && (c0 + c1) > 0)
      base = atomicAdd(&cnt[e], c0 + c1);
    base = __shfl(base, 0, 64);
    if (e0 == e) s0 = base + __popcll(m0 & below);
    if (e1 == e) s1 = base + c0 + __popcll(m1 & below);
  }
  tokEnc[2 * t + 0] = (e0 << 16) | s0;
  tokEnc[2 * t + 1] = (e1 << 16) | s1;
  tIdx[e0 * T_TOK + s0] = t;
  tIdx[e1 * T_TOK + s1] = t;
}

// ---------------------------------------------------------------------------
// GEMM1: h[row][f] = silu( sum_d xb[tok(row)][d] * w1t[e][f][d] )   (bf16 out)
// 128x128 tile, BK=64, COUNTED-VMCNT double buffer:
//   stage(next tile) -> s_waitcnt vmcnt(8) [own prev-tile loads done, NOT the
//   8 just issued] -> raw s_barrier -> ds_read+MFMA(cur) -> lgkmcnt(0) ->
//   raw s_barrier.  No vmcnt(0) drain in the loop (round-1's failure mode).
// Each wave issues exactly 8 gl_lds16 per stage; vmcnt is per-wave, barrier
// makes completion block-wide. lgkmcnt(0) before trailing barrier ensures
// LDS reads drain before the next stage overwrites (rule-18 WAR guard).
// LDS 64KB -> 2 blk/CU. XCD-pinned decode unchanged (g&7 = expert).
// ---------------------------------------------------------------------------
__global__ __launch_bounds__(256, 2) void gemm1_kernel(
    const unsigned short* __restrict__ xb,   // [T][D] bf16
    const unsigned short* __restrict__ w1t,  // [E][F][D] bf16
    unsigned short* __restrict__ h,          // [2T][F] bf16 (compacted)
    const int* __restrict__ tIdx, const int* __restrict__ cnt)
{
  // decode swizzled 1-D id: g = (phase*512 + m*8 + nl)*8 + e
  int g = blockIdx.x;
  int e = g & 7;
  int b = g >> 3;              // 0..1023
  int phase = b >> 9;          // 0..1  (n-half)
  int m = (b >> 3) & 63;       // 0..63 (M-tile)
  int nl = b & 7;              // 0..7  (n within half)
  int count = cnt[e];
  int r0 = m * 128;
  if (r0 >= count) return;
  int n0 = (phase * 8 + nl) * 128;

  __shared__ __align__(16) unsigned short As[2][8][128][8];   // 32 KB
  __shared__ __align__(16) unsigned short Bs[2][8][128][8];   // 32 KB

  int tid = threadIdx.x, lane = tid & 63, w = tid >> 6;
  int wr = w >> 1, wc = w & 1;
  int quad = lane >> 4, li = lane & 15;

  const unsigned short* ag[2];
  const unsigned short* bg[2];
  for (int c = 0; c < 2; ++c) {
    int mm = c * 64 + lane;
    int r = r0 + mm; if (r > count - 1) r = count - 1;
    ag[c] = xb + (size_t)tIdx[e * T_TOK + r] * DIM;
    bg[c] = w1t + ((size_t)e * FF + (n0 + mm)) * DIM;
  }

  floatx4 acc[4][4];
  for (int mi = 0; mi < 4; ++mi)
    for (int ni = 0; ni < 4; ++ni)
      for (int q = 0; q < 4; ++q) acc[mi][ni][q] = 0.0f;

  auto stage = [&](int buf, int k0) {   // 8 gl_lds16 per wave
    for (int kk = 0; kk < 2; ++kk) {
      int kq = w + kk * 4;
      gl_lds16(ag[0] + k0 + kq * 8, &As[buf][kq][0][0]);
      gl_lds16(ag[1] + k0 + kq * 8, &As[buf][kq][64][0]);
      gl_lds16(bg[0] + k0 + kq * 8, &Bs[buf][kq][0][0]);
      gl_lds16(bg[1] + k0 + kq * 8, &Bs[buf][kq][64][0]);
    }
  };

  stage(0, 0);
  int cur = 0;
  for (int k0 = 0; k0 < DIM; k0 += 64) {
    if (k0 + 64 < DIM) {
      stage(cur ^ 1, k0 + 64);                          // issue next tile
      asm volatile("s_waitcnt vmcnt(8)" ::: "memory");  // own cur-tile done
    } else {
      asm volatile("s_waitcnt vmcnt(0)" ::: "memory");  // tail drain
    }
    asm volatile("s_barrier" ::: "memory");             // cur tile ready (all)
    for (int ks = 0; ks < 2; ++ks) {
      bf16x8 af[4], bf[4];
      for (int mi = 0; mi < 4; ++mi)
        af[mi] = *(const bf16x8*)&As[cur][ks * 4 + quad][wr * 64 + mi * 16 + li][0];
      for (int ni = 0; ni < 4; ++ni)
        bf[ni] = *(const bf16x8*)&Bs[cur][ks * 4 + quad][wc * 64 + ni * 16 + li][0];
      for (int mi = 0; mi < 4; ++mi)
        for (int ni = 0; ni < 4; ++ni)
          acc[mi][ni] = __builtin_amdgcn_mfma_f32_16x16x32_bf16(
              af[mi], bf[ni], acc[mi][ni], 0, 0, 0);
    }
    asm volatile("s_waitcnt lgkmcnt(0)" ::: "memory");  // LDS reads drained
    asm volatile("s_barrier" ::: "memory");             // before cur overwrite
    cur ^= 1;
  }

  size_t hb = 0;
  for (int i = 0; i < e; ++i) hb += cnt[i];
  for (int mi = 0; mi < 4; ++mi) {
    int rowb = wr * 64 + mi * 16 + quad * 4;
    for (int rr = 0; rr < 4; ++rr) {
      int r = r0 + rowb + rr;
      if (r >= count) continue;
      unsigned short* hrow = h + (hb + r) * FF + n0 + wc * 64 + li;
      for (int ni = 0; ni < 4; ++ni) {
        float v = acc[mi][ni][rr];
        float s = v / (1.0f + __expf(-v));   // silu
        hrow[ni * 16] = f2bf(s);
      }
    }
  }
}

// ---------------------------------------------------------------------------
// GEMM2: yv[row][d] = sum_f h[row][f] * w2t[e][d][f]    (f32 out)
// Same counted-vmcnt double-buffered structure.
// ---------------------------------------------------------------------------
__global__ __launch_bounds__(256, 2) void gemm2_kernel(
    const unsigned short* __restrict__ h,    // [2T][F] bf16
    const unsigned short* __restrict__ w2t,  // [E][D][F] bf16
    float* __restrict__ yv,                  // [2T][D] f32
    const int* __restrict__ cnt)
{
  // decode swizzled 1-D id: g = (phase*256 + m*4 + nl)*8 + e
  int g = blockIdx.x;
  int e = g & 7;
  int b = g >> 3;              // 0..511
  int phase = b >> 8;          // 0..1
  int m = (b >> 2) & 63;       // 0..63
  int nl = b & 3;              // 0..3
  int count = cnt[e];
  int r0 = m * 128;
  if (r0 >= count) return;
  int n0 = (phase * 4 + nl) * 128;

  __shared__ __align__(16) unsigned short As[2][8][128][8];   // 32 KB
  __shared__ __align__(16) unsigned short Bs[2][8][128][8];   // 32 KB

  int tid = threadIdx.x, lane = tid & 63, w = tid >> 6;
  int wr = w >> 1, wc = w & 1;
  int quad = lane >> 4, li = lane & 15;
  size_t yb = 0;
  for (int i = 0; i < e; ++i) yb += cnt[i];

  const unsigned short* ag[2];
  const unsigned short* bg[2];
  for (int c = 0; c < 2; ++c) {
    int mm = c * 64 + lane;
    int r = r0 + mm; if (r > count - 1) r = count - 1;
    ag[c] = h + (yb + r) * FF;
    bg[c] = w2t + ((size_t)e * DIM + (n0 + mm)) * FF;
  }

  floatx4 acc[4][4];
  for (int mi = 0; mi < 4; ++mi)
    for (int ni = 0; ni < 4; ++ni)
      for (int q = 0; q < 4; ++q) acc[mi][ni][q] = 0.0f;

  auto stage = [&](int buf, int k0) {   // 8 gl_lds16 per wave
    for (int kk = 0; kk < 2; ++kk) {
      int kq = w + kk * 4;
      gl_lds16(ag[0] + k0 + kq * 8, &As[buf][kq][0][0]);
      gl_lds16(ag[1] + k0 + kq * 8, &As[buf][kq][64][0]);
      gl_lds16(bg[0] + k0 + kq * 8, &Bs[buf][kq][0][0]);
      gl_lds16(bg[1] + k0 + kq * 8, &Bs[buf][kq][64][0]);
    }
  };

  stage(0, 0);
  int cur = 0;
  for (int k0 = 0; k0 < FF; k0 += 64) {
    if (k0 + 64 < FF) {
      stage(cur ^ 1, k0 + 64);
      asm volatile("s_waitcnt vmcnt(8)" ::: "memory");
    } else {
      asm volatile("s_waitcnt vmcnt(0)" ::: "memory");
    }
    asm volatile("s_barrier" ::: "memory");
    for (int ks = 0; ks < 2; ++ks) {
      bf16x8 af[4], bf[4];
      for (int mi = 0; mi < 4; ++mi)
        af[mi] = *(const bf16x8*)&As[cur][ks * 4 + quad][wr * 64 + mi * 16 + li][0];
      for (int ni = 0; ni < 4; ++ni)
        bf[ni] = *(const bf16x8*)&Bs[cur][ks * 4 + quad][wc * 64 + ni * 16 + li][0];
      for (int mi = 0; mi < 4; ++mi)
        for (int ni = 0; ni < 4; ++ni)
          acc[mi][ni] = __builtin_amdgcn_mfma_f32_16x16x32_bf16(
              af[mi], bf[ni], acc[mi][ni], 0, 0, 0);
    }
    asm volatile("s_waitcnt lgkmcnt(0)" ::: "memory");
    asm volatile("s_barrier" ::: "memory");
    cur ^= 1;
  }

  for (int mi = 0; mi < 4; ++mi) {
    int rowb = wr * 64 + mi * 16 + quad * 4;
    for (int rr = 0; rr < 4; ++rr) {
      int r = r0 + rowb + rr;
      if (r >= count) continue;
      float* yrow = yv + (yb + r) * DIM + n0 + wc * 64 + li;
      for (int ni = 0; ni < 4; ++ni)
        yrow[ni * 16] = acc[mi][ni][rr];
    }
  }
}

// ---------------------------------------------------------------------------
// Combine: out[t] = w0 * yv[row0] + w1 * yv[row1]
// ---------------------------------------------------------------------------
__global__ __launch_bounds__(256) void combine_kernel(
    const float* __restrict__ yv, const int* __restrict__ tokEnc,
    const float* __restrict__ tokW, const int* __restrict__ cnt,
    float* __restrict__ out)
{
  int t = blockIdx.x;
  int i = threadIdx.x;   // 256 threads x float4 = 1024 = D
  int enc0 = tokEnc[2 * t + 0], enc1 = tokEnc[2 * t + 1];
  float w0 = tokW[2 * t + 0], w1 = tokW[2 * t + 1];
  int x0 = enc0 >> 16, x1 = enc1 >> 16;
  int off0 = 0, off1 = 0, a = 0;
  for (int e = 0; e < NE; ++e) {
    if (e == x0) off0 = a;
    if (e == x1) off1 = a;
    a += cnt[e];
  }
  size_t row0 = (size_t)off0 + (enc0 & 0xFFFF);
  size_t row1 = (size_t)off1 + (enc1 & 0xFFFF);
  float4 va = ((const float4*)(yv + row0 * DIM))[i];
  float4 vb = ((const float4*)(yv + row1 * DIM))[i];
  float4 o;
  o.x = w0 * va.x + w1 * vb.x;
  o.y = w0 * va.y + w1 * vb.y;
  o.z = w0 * va.z + w1 * vb.z;
  o.w = w0 * va.w + w1 * vb.w;
  ((float4*)(out + (size_t)t * DIM))[i] = o;
}

// ---------------------------------------------------------------------------
extern "C" void kernel_launch(void* const* d_in, const int* in_sizes, int n_in,
                              void* d_out, int out_size, void* d_ws, size_t ws_size,
                              hipStream_t stream)
{
  const float* x  = (const float*)d_in[0];   // [T][D]
  const float* gw = (const float*)d_in[1];   // [D][E]
  const float* w1 = (const float*)d_in[2];   // [E][D][F]
  const float* w2 = (const float*)d_in[3];   // [E][F][D]
  float* out = (float*)d_out;                // [T][D]

  // workspace carve-up (256B aligned)
  size_t o = 0;
  auto alloc = [&](size_t bytes) {
    void* p = (char*)d_ws + o;
    o += (bytes + 255) & ~(size_t)255;
    return p;
  };
  unsigned short* xb   = (unsigned short*)alloc((size_t)T_TOK * DIM * 2);      // 16.8 MB
  unsigned short* w1t  = (unsigned short*)alloc((size_t)NE * DIM * FF * 2);    // 33.6 MB
  unsigned short* w2t  = (unsigned short*)alloc((size_t)NE * DIM * FF * 2);    // 33.6 MB
  unsigned short* hbuf = (unsigned short*)alloc((size_t)T_TOK * TOPK * FF * 2);// 67.1 MB
  float*          yv   = (float*)alloc((size_t)T_TOK * TOPK * DIM * 4);        // 67.1 MB
  int*   tIdx   = (int*)alloc((size_t)NE * T_TOK * 4);
  int*   tokEnc = (int*)alloc((size_t)2 * T_TOK * 4);
  float* tokW   = (float*)alloc((size_t)2 * T_TOK * 4);
  int*   tokExp = (int*)alloc((size_t)T_TOK * 4);
  int*   cnt    = (int*)alloc((size_t)NE * 4);

  // both weight transposes in ONE launch (z = expert | sel<<3), 64x64 tiles
  transpose2_bf16_kernel<<<dim3(512, 1, 2 * NE), 256, 0, stream>>>(w1, w1t, w2, w2t);

  gate_kernel<<<T_TOK / 4, 256, 0, stream>>>(x, gw, xb, tokExp, tokW, cnt);
  assign_kernel<<<T_TOK / 256, 256, 0, stream>>>(tokExp, tokEnc, tIdx, cnt);

  // XCD-pinned swizzled 1-D grids (g & 7 = XCD = expert)
  gemm1_kernel<<<8192, 256, 0, stream>>>(xb, w1t, hbuf, tIdx, cnt);
  gemm2_kernel<<<4096, 256, 0, stream>>>(hbuf, w2t, yv, cnt);
  combine_kernel<<<T_TOK, 256, 0, stream>>>(yv, tokEnc, tokW, cnt, out);
}

// Round 9
// 538.108 us; speedup vs baseline: 1.1725x; 1.0595x over previous
//
#include <hip/hip_runtime.h>
#include <cstdint>
#include <cstddef>

// Problem constants (B=2, S=4096 -> T=8192 tokens)
#define T_TOK 8192
#define DIM   1024   // D
#define NE    8      // experts
#define FF    2048   // F
#define TOPK  2

typedef __bf16 bf16x8 __attribute__((ext_vector_type(8)));
typedef float  floatx4 __attribute__((ext_vector_type(4)));

__device__ __forceinline__ unsigned short f2bf(float f) {
  unsigned int u = __float_as_uint(f);
  unsigned int r = 0x7FFFu + ((u >> 16) & 1u);   // round-to-nearest-even
  return (unsigned short)((u + r) >> 16);
}

__device__ __forceinline__ void gl_lds16(const void* g, void* l) {
  __builtin_amdgcn_global_load_lds(
      (__attribute__((address_space(1))) void*)g,
      (__attribute__((address_space(3))) void*)l,
      16, 0, 0);
}

// ---------------------------------------------------------------------------
// PREP (fused): one launch does BOTH weight transposes AND gating.
//   b <  2048          : gate for tokens b*4..b*4+3 (32KB LDS for gwT)
//   b >= 2048          : 64x64 transpose tile (b-2048); z = tile>>9 selects
//                        expert+which-weight, bx = tile&511 the tile.
// Independent work; block-uniform branch; shared LDS block reused per branch.
// Saves one dispatch + overlaps transpose HBM streaming with gate compute.
// ---------------------------------------------------------------------------
__global__ __launch_bounds__(256) void prep_kernel(
    const float* __restrict__ w1, unsigned short* __restrict__ w1t,
    const float* __restrict__ w2, unsigned short* __restrict__ w2t,
    const float* __restrict__ x, const float* __restrict__ gw,
    unsigned short* __restrict__ xb, int* __restrict__ tokExp,
    float* __restrict__ tokW, int* __restrict__ cnt)
{
  __shared__ __align__(16) char smem[NE * DIM * 4];   // 32 KB (max of both uses)
  int tid = threadIdx.x;
  int b = blockIdx.x;

  if (b >= T_TOK / 4) {
    // ---------------- transpose branch (8192 tiles) ----------------
    unsigned short (*tile)[68] = (unsigned short (*)[68])smem;   // 8.5 KB
    int t64 = b - T_TOK / 4;
    int z = t64 >> 9;                     // 0..15
    int e = z & 7, sel = z >> 3;
    int R = sel ? FF : DIM;
    int C = sel ? DIM : FF;
    const float* inp = (sel ? w2 : w1) + (size_t)e * R * C;
    unsigned short* op = (sel ? w2t : w1t) + (size_t)e * R * C;
    int nc = C >> 6;                      // 64-col tiles along C
    int bx = t64 & 511;
    int c0 = (bx % nc) * 64, r0 = (bx / nc) * 64;
    int t4 = tid & 15, ry = tid >> 4;     // 16 x 16
    #pragma unroll
    for (int p = 0; p < 4; ++p) {
      int r = ry + p * 16;
      float4 v = *(const float4*)&inp[(size_t)(r0 + r) * C + c0 + t4 * 4];
      ushort4 sv;
      sv.x = f2bf(v.x); sv.y = f2bf(v.y); sv.z = f2bf(v.z); sv.w = f2bf(v.w);
      *(ushort4*)&tile[r][t4 * 4] = sv;
    }
    __syncthreads();
    #pragma unroll
    for (int p = 0; p < 4; ++p) {
      int cy = ry + p * 16;
      ushort4 s;
      s.x = tile[t4 * 4 + 0][cy];
      s.y = tile[t4 * 4 + 1][cy];
      s.z = tile[t4 * 4 + 2][cy];
      s.w = tile[t4 * 4 + 3][cy];
      *(ushort4*)&op[(size_t)(c0 + cy) * R + r0 + t4 * 4] = s;
    }
    return;
  }

  // ---------------- gate branch (2048 blocks) ----------------
  float (*gwT)[DIM] = (float (*)[DIM])smem;   // 32 KB
  if (b == 0 && tid < NE) cnt[tid] = 0;
  for (int i = tid; i < DIM * NE; i += 256) {
    int d = i >> 3, e = i & 7;
    gwT[e][d] = gw[i];
  }
  __syncthreads();

  int wv = tid >> 6, lane = tid & 63;
  int t = b * 4 + wv;
  const float* xrow = x + (size_t)t * DIM;
  unsigned short* xbrow = xb + (size_t)t * DIM;

  double acc[NE];
  for (int e = 0; e < NE; ++e) acc[e] = 0.0;

  for (int j = 0; j < 4; ++j) {
    float4 xv = ((const float4*)xrow)[j * 64 + lane];
    ushort4 s;
    s.x = f2bf(xv.x); s.y = f2bf(xv.y); s.z = f2bf(xv.z); s.w = f2bf(xv.w);
    ((ushort4*)xbrow)[j * 64 + lane] = s;
    double xd0 = (double)xv.x, xd1 = (double)xv.y;
    double xd2 = (double)xv.z, xd3 = (double)xv.w;
    for (int e = 0; e < NE; ++e) {
      float4 g = ((const float4*)&gwT[e][0])[j * 64 + lane];
      acc[e] += xd0 * (double)g.x + xd1 * (double)g.y +
                xd2 * (double)g.z + xd3 * (double)g.w;
    }
  }

  for (int s = 32; s > 0; s >>= 1)
    for (int e = 0; e < NE; ++e)
      acc[e] += __shfl_down(acc[e], s, 64);

  if (lane == 0) {
    int e0 = 0; double v0 = acc[0];
    for (int e = 1; e < NE; ++e) if (acc[e] > v0) { v0 = acc[e]; e0 = e; }
    int e1 = -1; double v1 = -1.0e300;
    for (int e = 0; e < NE; ++e) {
      if (e == e0) continue;
      if (acc[e] > v1) { v1 = acc[e]; e1 = e; }
    }
    float a = (float)v0, bb = (float)v1;
    float eb = __expf(bb - a);
    float den = 1.0f + eb;
    tokExp[t] = e0 | (e1 << 8);
    tokW[2 * t + 0] = 1.0f / den;
    tokW[2 * t + 1] = eb / den;
  }
}

// ---------------------------------------------------------------------------
// Gating pass 2 (PARALLEL): ballot ranks + ONE atomicAdd per expert per wave.
// Slot order nondeterministic but output bitwise invariant.
// ---------------------------------------------------------------------------
__global__ __launch_bounds__(256) void assign_kernel(
    const int* __restrict__ tokExp, int* __restrict__ tokEnc,
    int* __restrict__ tIdx, int* __restrict__ cnt)
{
  int t = blockIdx.x * 256 + threadIdx.x;
  int lane = threadIdx.x & 63;
  unsigned long long below = (1ull << lane) - 1ull;
  int enc = tokExp[t];
  int e0 = enc & 0xFF, e1 = (enc >> 8) & 0xFF;
  int s0 = 0, s1 = 0;
  for (int e = 0; e < NE; ++e) {
    unsigned long long m0 = __ballot(e0 == e);
    unsigned long long m1 = __ballot(e1 == e);
    int c0 = __popcll(m0), c1 = __popcll(m1);
    int base = 0;
    if (lane == 0 && (c0 + c1) > 0)
      base = atomicAdd(&cnt[e], c0 + c1);
    base = __shfl(base, 0, 64);
    if (e0 == e) s0 = base + __popcll(m0 & below);
    if (e1 == e) s1 = base + c0 + __popcll(m1 & below);
  }
  tokEnc[2 * t + 0] = (e0 << 16) | s0;
  tokEnc[2 * t + 1] = (e1 << 16) | s1;
  tIdx[e0 * T_TOK + s0] = t;
  tIdx[e1 * T_TOK + s1] = t;
}

// ---------------------------------------------------------------------------
// GEMM1: h[row][f] = silu( sum_d xb[tok(row)][d] * w1t[e][f][d] )   (bf16 out)
// MEASURED-BEST (round 0/4): 128x128 tile, BK=64, single-buffer 2-barrier
// K-loop, 32 KB LDS, 4 blk/CU -> cross-block overlap hides load latency.
// 4 pipelining variants (r1,r2,r7,r8) all measured worse; do not re-add.
// ---------------------------------------------------------------------------
__global__ __launch_bounds__(256, 4) void gemm1_kernel(
    const unsigned short* __restrict__ xb,   // [T][D] bf16
    const unsigned short* __restrict__ w1t,  // [E][F][D] bf16
    unsigned short* __restrict__ h,          // [2T][F] bf16 (compacted)
    const int* __restrict__ tIdx, const int* __restrict__ cnt)
{
  // decode swizzled 1-D id: g = (phase*512 + m*8 + nl)*8 + e
  int g = blockIdx.x;
  int e = g & 7;
  int b = g >> 3;              // 0..1023
  int phase = b >> 9;          // 0..1  (n-half)
  int m = (b >> 3) & 63;       // 0..63 (M-tile)
  int nl = b & 7;              // 0..7  (n within half)
  int count = cnt[e];
  int r0 = m * 128;
  if (r0 >= count) return;
  int n0 = (phase * 8 + nl) * 128;

  __shared__ __align__(16) unsigned short As[8][128][8];   // 16 KB
  __shared__ __align__(16) unsigned short Bs[8][128][8];   // 16 KB

  int tid = threadIdx.x, lane = tid & 63, w = tid >> 6;
  int wr = w >> 1, wc = w & 1;
  int quad = lane >> 4, li = lane & 15;

  const unsigned short* ag[2];
  const unsigned short* bg[2];
  for (int c = 0; c < 2; ++c) {
    int mm = c * 64 + lane;
    int r = r0 + mm; if (r > count - 1) r = count - 1;
    ag[c] = xb + (size_t)tIdx[e * T_TOK + r] * DIM;
    bg[c] = w1t + ((size_t)e * FF + (n0 + mm)) * DIM;
  }

  floatx4 acc[4][4];
  for (int mi = 0; mi < 4; ++mi)
    for (int ni = 0; ni < 4; ++ni)
      for (int q = 0; q < 4; ++q) acc[mi][ni][q] = 0.0f;

  for (int k0 = 0; k0 < DIM; k0 += 64) {
    __syncthreads();
    for (int kk = 0; kk < 2; ++kk) {
      int kq = w + kk * 4;
      gl_lds16(ag[0] + k0 + kq * 8, &As[kq][0][0]);
      gl_lds16(ag[1] + k0 + kq * 8, &As[kq][64][0]);
      gl_lds16(bg[0] + k0 + kq * 8, &Bs[kq][0][0]);
      gl_lds16(bg[1] + k0 + kq * 8, &Bs[kq][64][0]);
    }
    __syncthreads();
    for (int ks = 0; ks < 2; ++ks) {
      bf16x8 af[4], bf[4];
      for (int mi = 0; mi < 4; ++mi)
        af[mi] = *(const bf16x8*)&As[ks * 4 + quad][wr * 64 + mi * 16 + li][0];
      for (int ni = 0; ni < 4; ++ni)
        bf[ni] = *(const bf16x8*)&Bs[ks * 4 + quad][wc * 64 + ni * 16 + li][0];
      for (int mi = 0; mi < 4; ++mi)
        for (int ni = 0; ni < 4; ++ni)
          acc[mi][ni] = __builtin_amdgcn_mfma_f32_16x16x32_bf16(
              af[mi], bf[ni], acc[mi][ni], 0, 0, 0);
    }
  }

  size_t hb = 0;
  for (int i = 0; i < e; ++i) hb += cnt[i];
  for (int mi = 0; mi < 4; ++mi) {
    int rowb = wr * 64 + mi * 16 + quad * 4;
    for (int rr = 0; rr < 4; ++rr) {
      int r = r0 + rowb + rr;
      if (r >= count) continue;
      unsigned short* hrow = h + (hb + r) * FF + n0 + wc * 64 + li;
      for (int ni = 0; ni < 4; ++ni) {
        float v = acc[mi][ni][rr];
        float s = v / (1.0f + __expf(-v));   // silu
        hrow[ni * 16] = f2bf(s);
      }
    }
  }
}

// ---------------------------------------------------------------------------
// GEMM2: yv[row][d] = sum_f h[row][f] * w2t[e][d][f]    (f32 out)
// MEASURED-BEST (round 0/4) structure.
// ---------------------------------------------------------------------------
__global__ __launch_bounds__(256, 4) void gemm2_kernel(
    const unsigned short* __restrict__ h,    // [2T][F] bf16
    const unsigned short* __restrict__ w2t,  // [E][D][F] bf16
    float* __restrict__ yv,                  // [2T][D] f32
    const int* __restrict__ cnt)
{
  // decode swizzled 1-D id: g = (phase*256 + m*4 + nl)*8 + e
  int g = blockIdx.x;
  int e = g & 7;
  int b = g >> 3;              // 0..511
  int phase = b >> 8;          // 0..1
  int m = (b >> 2) & 63;       // 0..63
  int nl = b & 3;              // 0..3
  int count = cnt[e];
  int r0 = m * 128;
  if (r0 >= count) return;
  int n0 = (phase * 4 + nl) * 128;

  __shared__ __align__(16) unsigned short As[8][128][8];   // 16 KB
  __shared__ __align__(16) unsigned short Bs[8][128][8];   // 16 KB

  int tid = threadIdx.x, lane = tid & 63, w = tid >> 6;
  int wr = w >> 1, wc = w & 1;
  int quad = lane >> 4, li = lane & 15;
  size_t yb = 0;
  for (int i = 0; i < e; ++i) yb += cnt[i];

  const unsigned short* ag[2];
  const unsigned short* bg[2];
  for (int c = 0; c < 2; ++c) {
    int mm = c * 64 + lane;
    int r = r0 + mm; if (r > count - 1) r = count - 1;
    ag[c] = h + (yb + r) * FF;
    bg[c] = w2t + ((size_t)e * DIM + (n0 + mm)) * FF;
  }

  floatx4 acc[4][4];
  for (int mi = 0; mi < 4; ++mi)
    for (int ni = 0; ni < 4; ++ni)
      for (int q = 0; q < 4; ++q) acc[mi][ni][q] = 0.0f;

  for (int k0 = 0; k0 < FF; k0 += 64) {
    __syncthreads();
    for (int kk = 0; kk < 2; ++kk) {
      int kq = w + kk * 4;
      gl_lds16(ag[0] + k0 + kq * 8, &As[kq][0][0]);
      gl_lds16(ag[1] + k0 + kq * 8, &As[kq][64][0]);
      gl_lds16(bg[0] + k0 + kq * 8, &Bs[kq][0][0]);
      gl_lds16(bg[1] + k0 + kq * 8, &Bs[kq][64][0]);
    }
    __syncthreads();
    for (int ks = 0; ks < 2; ++ks) {
      bf16x8 af[4], bf[4];
      for (int mi = 0; mi < 4; ++mi)
        af[mi] = *(const bf16x8*)&As[ks * 4 + quad][wr * 64 + mi * 16 + li][0];
      for (int ni = 0; ni < 4; ++ni)
        bf[ni] = *(const bf16x8*)&Bs[ks * 4 + quad][wc * 64 + ni * 16 + li][0];
      for (int mi = 0; mi < 4; ++mi)
        for (int ni = 0; ni < 4; ++ni)
          acc[mi][ni] = __builtin_amdgcn_mfma_f32_16x16x32_bf16(
              af[mi], bf[ni], acc[mi][ni], 0, 0, 0);
    }
  }

  for (int mi = 0; mi < 4; ++mi) {
    int rowb = wr * 64 + mi * 16 + quad * 4;
    for (int rr = 0; rr < 4; ++rr) {
      int r = r0 + rowb + rr;
      if (r >= count) continue;
      float* yrow = yv + (yb + r) * DIM + n0 + wc * 64 + li;
      for (int ni = 0; ni < 4; ++ni)
        yrow[ni * 16] = acc[mi][ni][rr];
    }
  }
}

// ---------------------------------------------------------------------------
// Combine: out[t] = w0 * yv[row0] + w1 * yv[row1]
// ---------------------------------------------------------------------------
__global__ __launch_bounds__(256) void combine_kernel(
    const float* __restrict__ yv, const int* __restrict__ tokEnc,
    const float* __restrict__ tokW, const int* __restrict__ cnt,
    float* __restrict__ out)
{
  int t = blockIdx.x;
  int i = threadIdx.x;   // 256 threads x float4 = 1024 = D
  int enc0 = tokEnc[2 * t + 0], enc1 = tokEnc[2 * t + 1];
  float w0 = tokW[2 * t + 0], w1 = tokW[2 * t + 1];
  int x0 = enc0 >> 16, x1 = enc1 >> 16;
  int off0 = 0, off1 = 0, a = 0;
  for (int e = 0; e < NE; ++e) {
    if (e == x0) off0 = a;
    if (e == x1) off1 = a;
    a += cnt[e];
  }
  size_t row0 = (size_t)off0 + (enc0 & 0xFFFF);
  size_t row1 = (size_t)off1 + (enc1 & 0xFFFF);
  float4 va = ((const float4*)(yv + row0 * DIM))[i];
  float4 vb = ((const float4*)(yv + row1 * DIM))[i];
  float4 o;
  o.x = w0 * va.x + w1 * vb.x;
  o.y = w0 * va.y + w1 * vb.y;
  o.z = w0 * va.z + w1 * vb.z;
  o.w = w0 * va.w + w1 * vb.w;
  ((float4*)(out + (size_t)t * DIM))[i] = o;
}

// ---------------------------------------------------------------------------
extern "C" void kernel_launch(void* const* d_in, const int* in_sizes, int n_in,
                              void* d_out, int out_size, void* d_ws, size_t ws_size,
                              hipStream_t stream)
{
  const float* x  = (const float*)d_in[0];   // [T][D]
  const float* gw = (const float*)d_in[1];   // [D][E]
  const float* w1 = (const float*)d_in[2];   // [E][D][F]
  const float* w2 = (const float*)d_in[3];   // [E][F][D]
  float* out = (float*)d_out;                // [T][D]

  // workspace carve-up (256B aligned)
  size_t o = 0;
  auto alloc = [&](size_t bytes) {
    void* p = (char*)d_ws + o;
    o += (bytes + 255) & ~(size_t)255;
    return p;
  };
  unsigned short* xb   = (unsigned short*)alloc((size_t)T_TOK * DIM * 2);      // 16.8 MB
  unsigned short* w1t  = (unsigned short*)alloc((size_t)NE * DIM * FF * 2);    // 33.6 MB
  unsigned short* w2t  = (unsigned short*)alloc((size_t)NE * DIM * FF * 2);    // 33.6 MB
  unsigned short* hbuf = (unsigned short*)alloc((size_t)T_TOK * TOPK * FF * 2);// 67.1 MB
  float*          yv   = (float*)alloc((size_t)T_TOK * TOPK * DIM * 4);        // 67.1 MB
  int*   tIdx   = (int*)alloc((size_t)NE * T_TOK * 4);
  int*   tokEnc = (int*)alloc((size_t)2 * T_TOK * 4);
  float* tokW   = (float*)alloc((size_t)2 * T_TOK * 4);
  int*   tokExp = (int*)alloc((size_t)T_TOK * 4);
  int*   cnt    = (int*)alloc((size_t)NE * 4);

  // fused preamble: gate (blocks 0..2047) + both weight transposes (2048..10239)
  prep_kernel<<<T_TOK / 4 + 8192, 256, 0, stream>>>(
      w1, w1t, w2, w2t, x, gw, xb, tokExp, tokW, cnt);

  assign_kernel<<<T_TOK / 256, 256, 0, stream>>>(tokExp, tokEnc, tIdx, cnt);

  // XCD-pinned swizzled 1-D grids (g & 7 = XCD = expert)
  gemm1_kernel<<<8192, 256, 0, stream>>>(xb, w1t, hbuf, tIdx, cnt);
  gemm2_kernel<<<4096, 256, 0, stream>>>(hbuf, w2t, yv, cnt);
  combine_kernel<<<T_TOK, 256, 0, stream>>>(yv, tokEnc, tokW, cnt, out);
}